// Round 1
// baseline (898.343 us; speedup 1.0000x reference)
//
#include <hip/hip_runtime.h>
#include <math.h>

#define N_NODES 100000
#define N_EDGES 3200000
#define F_IN    512
#define HID     16
#define NCLS    7
#define ALPHA   0.1f
#define K_HOPS  10

#define SCAN_B  256
#define SCAN_NB ((N_NODES + SCAN_B - 1) / SCAN_B)   // 391

// ---- workspace layout (4-byte element offsets) ----
#define OFF_CNT   0u          // int[100000]
#define OFF_RP    100352u     // int[100001]
#define OFF_CUR   200704u     // int[100000]
#define OFF_BS    301056u     // int[512]
#define OFF_BSX   301568u     // int[512]
#define OFF_DINV  302080u     // float[100000]
#define OFF_COL   402432u     // int[3200000]
#define OFF_H0    3602432u    // float[100000*16]
#define OFF_H1    5202432u    // float[100000*16]
#define OFF_Z     6802432u    // float[100000*8]
// total = 7602432 elems = 30.4 MB

// ---------------- degree count ----------------
__global__ void k_count(const int* __restrict__ dst, int* __restrict__ cnt) {
    int e = blockIdx.x * blockDim.x + threadIdx.x;
    if (e < N_EDGES) atomicAdd(&cnt[dst[e]], 1);
}

// ---------------- block-wise exclusive scan ----------------
__global__ void k_scan1(const int* __restrict__ cnt, int* __restrict__ rp,
                        int* __restrict__ bsum) {
    __shared__ int s[SCAN_B];
    int i = blockIdx.x * SCAN_B + threadIdx.x;
    int v = (i < N_NODES) ? cnt[i] : 0;
    s[threadIdx.x] = v;
    __syncthreads();
    for (int off = 1; off < SCAN_B; off <<= 1) {
        int t = (threadIdx.x >= off) ? s[threadIdx.x - off] : 0;
        __syncthreads();
        s[threadIdx.x] += t;
        __syncthreads();
    }
    if (i < N_NODES) rp[i] = s[threadIdx.x] - v;   // exclusive
    if (threadIdx.x == SCAN_B - 1) bsum[blockIdx.x] = s[threadIdx.x];
}

__global__ void k_scan2(const int* __restrict__ bsum, int* __restrict__ bsumex) {
    __shared__ int s[512];
    int v = (threadIdx.x < SCAN_NB) ? bsum[threadIdx.x] : 0;
    s[threadIdx.x] = v;
    __syncthreads();
    for (int off = 1; off < 512; off <<= 1) {
        int t = (threadIdx.x >= off) ? s[threadIdx.x - off] : 0;
        __syncthreads();
        s[threadIdx.x] += t;
        __syncthreads();
    }
    bsumex[threadIdx.x] = s[threadIdx.x] - v;      // exclusive
}

__global__ void k_scan3(int* __restrict__ rp, const int* __restrict__ bsumex,
                        int* __restrict__ cursor) {
    int i = blockIdx.x * SCAN_B + threadIdx.x;
    if (i < N_NODES) {
        int v = rp[i] + bsumex[blockIdx.x];
        rp[i] = v;
        cursor[i] = v;
    }
    if (i == 0) rp[N_NODES] = N_EDGES;
}

// ---------------- dinv = rsqrt(deg + self-loop) ----------------
__global__ void k_dinv(const int* __restrict__ cnt, float* __restrict__ dinv) {
    int i = blockIdx.x * blockDim.x + threadIdx.x;
    if (i < N_NODES) dinv[i] = rsqrtf((float)(cnt[i] + 1));
}

// ---------------- CSR scatter ----------------
__global__ void k_scatter(const int* __restrict__ src, const int* __restrict__ dst,
                          int* __restrict__ cursor, int* __restrict__ col) {
    int e = blockIdx.x * blockDim.x + threadIdx.x;
    if (e < N_EDGES) {
        int d = dst[e];
        int pos = atomicAdd(&cursor[d], 1);
        col[pos] = src[e];
    }
}

// ---------------- h0 = x @ W1  (one thread per row) ----------------
__global__ void k_xw1(const float* __restrict__ x, const float* __restrict__ W,
                      float* __restrict__ h0) {
    int row = blockIdx.x * blockDim.x + threadIdx.x;
    if (row >= N_NODES) return;
    const float4* x4 = (const float4*)(x + (size_t)row * F_IN);
    float acc[HID];
#pragma unroll
    for (int c = 0; c < HID; c++) acc[c] = 0.f;
    for (int k4 = 0; k4 < F_IN / 4; k4++) {
        float4 xv = x4[k4];
        int k = k4 * 4;
#pragma unroll
        for (int j = 0; j < 4; j++) {
            float xj = (j == 0) ? xv.x : (j == 1) ? xv.y : (j == 2) ? xv.z : xv.w;
#pragma unroll
            for (int c = 0; c < HID; c++)
                acc[c] += xj * W[(k + j) * HID + c];   // uniform index -> s_load
        }
    }
    float4* o4 = (float4*)(h0 + (size_t)row * HID);
#pragma unroll
    for (int q = 0; q < HID / 4; q++) {
        float4 v;
        v.x = acc[q * 4 + 0]; v.y = acc[q * 4 + 1];
        v.z = acc[q * 4 + 2]; v.w = acc[q * 4 + 3];
        o4[q] = v;
    }
}

// ---------------- aggregate 1: h1 = relu(D^-1/2 (A+I) D^-1/2 h0 + b1) ----------------
// 16 lanes per node, lane = feature
__global__ void k_agg1(const float* __restrict__ h0, const int* __restrict__ rp,
                       const int* __restrict__ col, const float* __restrict__ dinv,
                       const float* __restrict__ b1, float* __restrict__ h1) {
    int t = blockIdx.x * blockDim.x + threadIdx.x;
    int node = t >> 4;
    int c = t & 15;
    if (node >= N_NODES) return;
    float dv = dinv[node];
    float acc = dv * h0[(size_t)node * HID + c];   // self loop
    int e0 = rp[node], e1 = rp[node + 1];
    for (int e = e0; e < e1; e++) {
        int s = col[e];
        acc += dinv[s] * h0[(size_t)s * HID + c];
    }
    float o = dv * acc + b1[c];
    h1[(size_t)node * HID + c] = fmaxf(o, 0.f);
}

// ---------------- 10 fused hops + z = h @ W2 ----------------
__global__ void k_hops(const float* __restrict__ h1, const float* __restrict__ Wl,
                       const float* __restrict__ bl, const float* __restrict__ W2,
                       float* __restrict__ z) {
    int node = blockIdx.x * blockDim.x + threadIdx.x;
    if (node >= N_NODES) return;
    float h[HID];
    const float4* h4 = (const float4*)(h1 + (size_t)node * HID);
#pragma unroll
    for (int q = 0; q < HID / 4; q++) {
        float4 v = h4[q];
        h[q * 4 + 0] = v.x; h[q * 4 + 1] = v.y;
        h[q * 4 + 2] = v.z; h[q * 4 + 3] = v.w;
    }
    for (int it = 0; it < K_HOPS; it++) {
        float tm[HID];
#pragma unroll
        for (int c = 0; c < HID; c++) tm[c] = bl[c];
#pragma unroll
        for (int k = 0; k < HID; k++) {
            float hk = h[k];
#pragma unroll
            for (int c = 0; c < HID; c++) tm[c] += hk * Wl[k * HID + c];
        }
#pragma unroll
        for (int c = 0; c < HID; c++)
            h[c] = ALPHA * fmaxf(tm[c], 0.f) + (1.f - ALPHA) * h[c];
    }
    float zz[8];
#pragma unroll
    for (int c = 0; c < 8; c++) zz[c] = 0.f;
#pragma unroll
    for (int k = 0; k < HID; k++) {
        float hk = h[k];
#pragma unroll
        for (int c = 0; c < NCLS; c++) zz[c] += hk * W2[k * NCLS + c];
    }
    float4* z4 = (float4*)(z + (size_t)node * 8);
    float4 v0, v1;
    v0.x = zz[0]; v0.y = zz[1]; v0.z = zz[2]; v0.w = zz[3];
    v1.x = zz[4]; v1.y = zz[5]; v1.z = zz[6]; v1.w = zz[7];
    z4[0] = v0; z4[1] = v1;
}

// ---------------- aggregate 2 + bias + log_softmax ----------------
// 8 lanes per node
__global__ void k_agg2(const float* __restrict__ z, const int* __restrict__ rp,
                       const int* __restrict__ col, const float* __restrict__ dinv,
                       const float* __restrict__ b2, float* __restrict__ out) {
    int t = blockIdx.x * blockDim.x + threadIdx.x;
    int node = t >> 3;
    int c = t & 7;
    if (node >= N_NODES) return;
    float dv = dinv[node];
    float acc = dv * z[(size_t)node * 8 + c];      // self loop (pad lane reads 0)
    int e0 = rp[node], e1 = rp[node + 1];
    for (int e = e0; e < e1; e++) {
        int s = col[e];
        acc += dinv[s] * z[(size_t)s * 8 + c];
    }
    float o = dv * acc + ((c < NCLS) ? b2[c] : 0.f);
    float val = (c < NCLS) ? o : -INFINITY;
    float m = val;
    m = fmaxf(m, __shfl_xor(m, 1));
    m = fmaxf(m, __shfl_xor(m, 2));
    m = fmaxf(m, __shfl_xor(m, 4));
    float ex = (c < NCLS) ? expf(o - m) : 0.f;
    float ss = ex;
    ss += __shfl_xor(ss, 1);
    ss += __shfl_xor(ss, 2);
    ss += __shfl_xor(ss, 4);
    if (c < NCLS) out[(size_t)node * NCLS + c] = o - m - logf(ss);
}

extern "C" void kernel_launch(void* const* d_in, const int* in_sizes, int n_in,
                              void* d_out, int out_size, void* d_ws, size_t ws_size,
                              hipStream_t stream) {
    const float* x  = (const float*)d_in[0];
    const int*   ei = (const int*)d_in[1];
    const float* W1 = (const float*)d_in[2];
    const float* b1 = (const float*)d_in[3];
    const float* Wl = (const float*)d_in[4];
    const float* bl = (const float*)d_in[5];
    const float* W2 = (const float*)d_in[6];
    const float* b2 = (const float*)d_in[7];
    float* out = (float*)d_out;

    int*   wsI = (int*)d_ws;
    float* wsF = (float*)d_ws;
    int*   cnt    = wsI + OFF_CNT;
    int*   rp     = wsI + OFF_RP;
    int*   cursor = wsI + OFF_CUR;
    int*   bsum   = wsI + OFF_BS;
    int*   bsumex = wsI + OFF_BSX;
    float* dinv   = wsF + OFF_DINV;
    int*   col    = wsI + OFF_COL;
    float* h0     = wsF + OFF_H0;
    float* h1     = wsF + OFF_H1;
    float* z      = wsF + OFF_Z;

    const int* src = ei;
    const int* dst = ei + N_EDGES;

    hipMemsetAsync(cnt, 0, N_NODES * sizeof(int), stream);

    int ebk = (N_EDGES + 255) / 256;
    k_count<<<ebk, 256, 0, stream>>>(dst, cnt);
    k_scan1<<<SCAN_NB, SCAN_B, 0, stream>>>(cnt, rp, bsum);
    k_scan2<<<1, 512, 0, stream>>>(bsum, bsumex);
    k_scan3<<<SCAN_NB, SCAN_B, 0, stream>>>(rp, bsumex, cursor);
    k_dinv<<<(N_NODES + 255) / 256, 256, 0, stream>>>(cnt, dinv);
    k_scatter<<<ebk, 256, 0, stream>>>(src, dst, cursor, col);
    k_xw1<<<(N_NODES + 255) / 256, 256, 0, stream>>>(x, W1, h0);
    k_agg1<<<(N_NODES * 16 + 255) / 256, 256, 0, stream>>>(h0, rp, col, dinv, b1, h1);
    k_hops<<<(N_NODES + 255) / 256, 256, 0, stream>>>(h1, Wl, bl, W2, z);
    k_agg2<<<(N_NODES * 8 + 255) / 256, 256, 0, stream>>>(z, rp, col, dinv, b2, out);
}

// Round 2
// 649.316 us; speedup vs baseline: 1.3835x; 1.3835x over previous
//
#include <hip/hip_runtime.h>
#include <math.h>

#define N_NODES 100000
#define N_EDGES 3200000
#define F_IN    512
#define HID     16
#define NCLS    7
#define ALPHA   0.1f
#define K_HOPS  10

// bucketing: 128 nodes per bucket
#define SHIFT   7
#define BWIDTH  128
#define NBUCK   ((N_NODES + BWIDTH - 1) / BWIDTH)   // 782
#define CHUNK   16384
#define A3_BLOCKS ((N_EDGES + CHUNK - 1) / CHUNK)   // 196

// ---- workspace layout (4-byte element offsets) ----
#define OFF_BCNT    0u         // int[782]
#define OFF_BSTART  1024u      // int[783]
#define OFF_BCUR    2048u      // int[782]
#define OFF_RP      3072u      // int[100001]
#define OFF_DINV    103424u    // float[100000]
#define OFF_COL     203776u    // int[3200000]
#define OFF_BINNED  3403776u   // uint[3200000]  (aliased with h0+h1 below)
#define OFF_H0      3403776u   // float[100000*16]   -- written AFTER k_csr reads binned
#define OFF_H1      5003776u   // float[100000*16]
#define OFF_Z       6603776u   // float[100000*8]
// total = 7403776 elems = 29.6 MB

// ---------------- A1: global bucket histogram ----------------
__global__ void k_bhist(const int* __restrict__ dst, int* __restrict__ bcnt) {
    __shared__ int h[NBUCK];
    int tid = threadIdx.x;
    for (int i = tid; i < NBUCK; i += 256) h[i] = 0;
    __syncthreads();
    for (int e = blockIdx.x * 256 + tid; e < N_EDGES; e += gridDim.x * 256)
        atomicAdd(&h[dst[e] >> SHIFT], 1);
    __syncthreads();
    for (int i = tid; i < NBUCK; i += 256) {
        int v = h[i];
        if (v) atomicAdd(&bcnt[i], v);
    }
}

// ---------------- A2: scan bucket counts ----------------
__global__ void k_bscan(const int* __restrict__ bcnt, int* __restrict__ bstart,
                        int* __restrict__ bcur) {
    __shared__ int s[1024];
    int tid = threadIdx.x;
    int v = (tid < NBUCK) ? bcnt[tid] : 0;
    s[tid] = v;
    __syncthreads();
    for (int off = 1; off < 1024; off <<= 1) {
        int t = (tid >= off) ? s[tid - off] : 0;
        __syncthreads();
        s[tid] += t;
        __syncthreads();
    }
    if (tid < NBUCK) {
        int ex = s[tid] - v;     // exclusive
        bstart[tid] = ex;
        bcur[tid] = ex;
    }
    if (tid == 0) bstart[NBUCK] = N_EDGES;
}

// ---------------- A3: binned scatter of packed edges ----------------
// binned[pos] = (dst&127)<<17 | src   (src < 2^17)
__global__ void k_bin(const int* __restrict__ src, const int* __restrict__ dst,
                      int* __restrict__ bcur, unsigned int* __restrict__ binned) {
    __shared__ int ha[1024];
    __shared__ int hb[1024];
    __shared__ int gbase[NBUCK];
    __shared__ int lcur[NBUCK];
    int tid = threadIdx.x;
    int e0 = blockIdx.x * CHUNK;
    int e1 = e0 + CHUNK;
    if (e1 > N_EDGES) e1 = N_EDGES;
    for (int i = tid; i < 1024; i += 256) ha[i] = 0;
    __syncthreads();
    for (int e = e0 + tid; e < e1; e += 256)
        atomicAdd(&ha[dst[e] >> SHIFT], 1);
    __syncthreads();
    // inclusive scan over 1024 (ping-pong, one barrier per step)
    int* a = ha;
    int* b = hb;
    for (int off = 1; off < 1024; off <<= 1) {
        for (int s = tid; s < 1024; s += 256)
            b[s] = a[s] + ((s >= off) ? a[s - off] : 0);
        __syncthreads();
        int* t = a; a = b; b = t;
    }
    // allocate per-bucket runs
    for (int s = tid; s < NBUCK; s += 256) {
        int c = a[s] - ((s > 0) ? a[s - 1] : 0);
        lcur[s] = 0;
        gbase[s] = c ? atomicAdd(&bcur[s], c) : 0;
    }
    __syncthreads();
    for (int e = e0 + tid; e < e1; e += 256) {
        int d = dst[e];
        int bk = d >> SHIFT;
        int idx = atomicAdd(&lcur[bk], 1);
        binned[gbase[bk] + idx] =
            ((unsigned int)(d & (BWIDTH - 1)) << 17) | (unsigned int)src[e];
    }
}

// ---------------- B: per-bucket CSR (count, scan, rp/dinv, col scatter) ----------------
__global__ void k_csr(const unsigned int* __restrict__ binned, const int* __restrict__ bstart,
                      int* __restrict__ rp, float* __restrict__ dinv, int* __restrict__ col) {
    __shared__ int cnt[BWIDTH];
    __shared__ int s[BWIDTH];
    __shared__ int cur[BWIDTH];
    int tid = threadIdx.x;
    int b = blockIdx.x;
    int base = b << SHIFT;
    int e0 = bstart[b], e1 = bstart[b + 1];
    if (tid < BWIDTH) cnt[tid] = 0;
    __syncthreads();
    for (int e = e0 + tid; e < e1; e += 256)
        atomicAdd(&cnt[binned[e] >> 17], 1);
    __syncthreads();
    int v = 0;
    if (tid < BWIDTH) { v = cnt[tid]; s[tid] = v; }
    __syncthreads();
    for (int off = 1; off < BWIDTH; off <<= 1) {
        int t = 0;
        if (tid < BWIDTH && tid >= off) t = s[tid - off];
        __syncthreads();
        if (tid < BWIDTH) s[tid] += t;
        __syncthreads();
    }
    if (tid < BWIDTH) {
        int ex = s[tid] - v;     // exclusive
        cur[tid] = ex;
        int node = base + tid;
        if (node < N_NODES) {
            rp[node] = e0 + ex;
            dinv[node] = rsqrtf((float)(v + 1));
        }
    }
    if (b == 0 && tid == 0) rp[N_NODES] = N_EDGES;
    __syncthreads();
    for (int e = e0 + tid; e < e1; e += 256) {
        unsigned int w = binned[e];
        int ln = (int)(w >> 17);
        int p = atomicAdd(&cur[ln], 1);
        col[e0 + p] = (int)(w & 0x1FFFFu);
    }
}

// ---------------- h0 = x @ W1  (one thread per row) ----------------
__global__ void k_xw1(const float* __restrict__ x, const float* __restrict__ W,
                      float* __restrict__ h0) {
    int row = blockIdx.x * blockDim.x + threadIdx.x;
    if (row >= N_NODES) return;
    const float4* x4 = (const float4*)(x + (size_t)row * F_IN);
    float acc[HID];
#pragma unroll
    for (int c = 0; c < HID; c++) acc[c] = 0.f;
    for (int k4 = 0; k4 < F_IN / 4; k4++) {
        float4 xv = x4[k4];
        int k = k4 * 4;
#pragma unroll
        for (int j = 0; j < 4; j++) {
            float xj = (j == 0) ? xv.x : (j == 1) ? xv.y : (j == 2) ? xv.z : xv.w;
#pragma unroll
            for (int c = 0; c < HID; c++)
                acc[c] += xj * W[(k + j) * HID + c];   // uniform index -> s_load
        }
    }
    float4* o4 = (float4*)(h0 + (size_t)row * HID);
#pragma unroll
    for (int q = 0; q < HID / 4; q++) {
        float4 v;
        v.x = acc[q * 4 + 0]; v.y = acc[q * 4 + 1];
        v.z = acc[q * 4 + 2]; v.w = acc[q * 4 + 3];
        o4[q] = v;
    }
}

// ---------------- aggregate 1: h1 = relu(D^-1/2 (A+I) D^-1/2 h0 + b1) ----------------
__global__ void k_agg1(const float* __restrict__ h0, const int* __restrict__ rp,
                       const int* __restrict__ col, const float* __restrict__ dinv,
                       const float* __restrict__ b1, float* __restrict__ h1) {
    int t = blockIdx.x * blockDim.x + threadIdx.x;
    int node = t >> 4;
    int c = t & 15;
    if (node >= N_NODES) return;
    float dv = dinv[node];
    float acc = dv * h0[(size_t)node * HID + c];   // self loop
    int e0 = rp[node], e1 = rp[node + 1];
    for (int e = e0; e < e1; e++) {
        int s = col[e];
        acc += dinv[s] * h0[(size_t)s * HID + c];
    }
    float o = dv * acc + b1[c];
    h1[(size_t)node * HID + c] = fmaxf(o, 0.f);
}

// ---------------- 10 fused hops + z = h @ W2 ----------------
__global__ void k_hops(const float* __restrict__ h1, const float* __restrict__ Wl,
                       const float* __restrict__ bl, const float* __restrict__ W2,
                       float* __restrict__ z) {
    int node = blockIdx.x * blockDim.x + threadIdx.x;
    if (node >= N_NODES) return;
    float h[HID];
    const float4* h4 = (const float4*)(h1 + (size_t)node * HID);
#pragma unroll
    for (int q = 0; q < HID / 4; q++) {
        float4 v = h4[q];
        h[q * 4 + 0] = v.x; h[q * 4 + 1] = v.y;
        h[q * 4 + 2] = v.z; h[q * 4 + 3] = v.w;
    }
    for (int it = 0; it < K_HOPS; it++) {
        float tm[HID];
#pragma unroll
        for (int c = 0; c < HID; c++) tm[c] = bl[c];
#pragma unroll
        for (int k = 0; k < HID; k++) {
            float hk = h[k];
#pragma unroll
            for (int c = 0; c < HID; c++) tm[c] += hk * Wl[k * HID + c];
        }
#pragma unroll
        for (int c = 0; c < HID; c++)
            h[c] = ALPHA * fmaxf(tm[c], 0.f) + (1.f - ALPHA) * h[c];
    }
    float zz[8];
#pragma unroll
    for (int c = 0; c < 8; c++) zz[c] = 0.f;
#pragma unroll
    for (int k = 0; k < HID; k++) {
        float hk = h[k];
#pragma unroll
        for (int c = 0; c < NCLS; c++) zz[c] += hk * W2[k * NCLS + c];
    }
    float4* z4 = (float4*)(z + (size_t)node * 8);
    float4 v0, v1;
    v0.x = zz[0]; v0.y = zz[1]; v0.z = zz[2]; v0.w = zz[3];
    v1.x = zz[4]; v1.y = zz[5]; v1.z = zz[6]; v1.w = zz[7];
    z4[0] = v0; z4[1] = v1;
}

// ---------------- aggregate 2 + bias + log_softmax ----------------
__global__ void k_agg2(const float* __restrict__ z, const int* __restrict__ rp,
                       const int* __restrict__ col, const float* __restrict__ dinv,
                       const float* __restrict__ b2, float* __restrict__ out) {
    int t = blockIdx.x * blockDim.x + threadIdx.x;
    int node = t >> 3;
    int c = t & 7;
    if (node >= N_NODES) return;
    float dv = dinv[node];
    float acc = dv * z[(size_t)node * 8 + c];      // self loop (pad lane reads 0)
    int e0 = rp[node], e1 = rp[node + 1];
    for (int e = e0; e < e1; e++) {
        int s = col[e];
        acc += dinv[s] * z[(size_t)s * 8 + c];
    }
    float o = dv * acc + ((c < NCLS) ? b2[c] : 0.f);
    float val = (c < NCLS) ? o : -INFINITY;
    float m = val;
    m = fmaxf(m, __shfl_xor(m, 1));
    m = fmaxf(m, __shfl_xor(m, 2));
    m = fmaxf(m, __shfl_xor(m, 4));
    float ex = (c < NCLS) ? expf(o - m) : 0.f;
    float ss = ex;
    ss += __shfl_xor(ss, 1);
    ss += __shfl_xor(ss, 2);
    ss += __shfl_xor(ss, 4);
    if (c < NCLS) out[(size_t)node * NCLS + c] = o - m - logf(ss);
}

extern "C" void kernel_launch(void* const* d_in, const int* in_sizes, int n_in,
                              void* d_out, int out_size, void* d_ws, size_t ws_size,
                              hipStream_t stream) {
    const float* x  = (const float*)d_in[0];
    const int*   ei = (const int*)d_in[1];
    const float* W1 = (const float*)d_in[2];
    const float* b1 = (const float*)d_in[3];
    const float* Wl = (const float*)d_in[4];
    const float* bl = (const float*)d_in[5];
    const float* W2 = (const float*)d_in[6];
    const float* b2 = (const float*)d_in[7];
    float* out = (float*)d_out;

    int*   wsI = (int*)d_ws;
    float* wsF = (float*)d_ws;
    int*          bcnt   = wsI + OFF_BCNT;
    int*          bstart = wsI + OFF_BSTART;
    int*          bcur   = wsI + OFF_BCUR;
    int*          rp     = wsI + OFF_RP;
    float*        dinv   = wsF + OFF_DINV;
    int*          col    = wsI + OFF_COL;
    unsigned int* binned = (unsigned int*)(wsI + OFF_BINNED);
    float*        h0     = wsF + OFF_H0;   // aliases binned (binned dead after k_csr)
    float*        h1     = wsF + OFF_H1;
    float*        z      = wsF + OFF_Z;

    const int* src = ei;
    const int* dst = ei + N_EDGES;

    hipMemsetAsync(bcnt, 0, NBUCK * sizeof(int), stream);

    k_bhist<<<512, 256, 0, stream>>>(dst, bcnt);
    k_bscan<<<1, 1024, 0, stream>>>(bcnt, bstart, bcur);
    k_bin<<<A3_BLOCKS, 256, 0, stream>>>(src, dst, bcur, binned);
    k_csr<<<NBUCK, 256, 0, stream>>>(binned, bstart, rp, dinv, col);
    k_xw1<<<(N_NODES + 255) / 256, 256, 0, stream>>>(x, W1, h0);
    k_agg1<<<(N_NODES * 16 + 255) / 256, 256, 0, stream>>>(h0, rp, col, dinv, b1, h1);
    k_hops<<<(N_NODES + 255) / 256, 256, 0, stream>>>(h1, Wl, bl, W2, z);
    k_agg2<<<(N_NODES * 8 + 255) / 256, 256, 0, stream>>>(z, rp, col, dinv, b2, out);
}

// Round 3
// 643.616 us; speedup vs baseline: 1.3958x; 1.0089x over previous
//
#include <hip/hip_runtime.h>
#include <math.h>

#define N_NODES 100000
#define N_EDGES 3200000
#define F_IN    512
#define HID     16
#define NCLS    7
#define ALPHA   0.1f
#define K_HOPS  10

// bucketing: 128 nodes per bucket
#define SHIFT   7
#define BWIDTH  128
#define NBUCK   ((N_NODES + BWIDTH - 1) / BWIDTH)   // 782
#define CHUNK   8192
#define A3_BLOCKS ((N_EDGES + CHUNK - 1) / CHUNK)   // 391

// ---- workspace layout (4-byte element offsets) ----
#define OFF_BCNT    0u         // int[782]
#define OFF_BSTART  1024u      // int[783]
#define OFF_BCUR    2048u      // int[782]
#define OFF_RP      3072u      // int[100001]
#define OFF_DINV    103424u    // float[100000]
#define OFF_COL     203776u    // int[3200000]
#define OFF_BINNED  3403776u   // uint[3200000]  (aliased with h0s below)
#define OFF_H0      3403776u   // float[100000*16]   -- written AFTER k_csr reads binned
#define OFF_H1      5003776u   // float[100000*16]
#define OFF_Z       6603776u   // float[100000*8]
// total = 7403776 elems = 29.6 MB

// ---------------- A1: global bucket histogram ----------------
__global__ void k_bhist(const int* __restrict__ dst, int* __restrict__ bcnt) {
    __shared__ int h[NBUCK];
    int tid = threadIdx.x;
    for (int i = tid; i < NBUCK; i += 256) h[i] = 0;
    __syncthreads();
    for (int e = blockIdx.x * 256 + tid; e < N_EDGES; e += gridDim.x * 256)
        atomicAdd(&h[dst[e] >> SHIFT], 1);
    __syncthreads();
    for (int i = tid; i < NBUCK; i += 256) {
        int v = h[i];
        if (v) atomicAdd(&bcnt[i], v);
    }
}

// ---------------- A2: scan bucket counts ----------------
__global__ void k_bscan(const int* __restrict__ bcnt, int* __restrict__ bstart,
                        int* __restrict__ bcur) {
    __shared__ int s[1024];
    int tid = threadIdx.x;
    int v = (tid < NBUCK) ? bcnt[tid] : 0;
    s[tid] = v;
    __syncthreads();
    for (int off = 1; off < 1024; off <<= 1) {
        int t = (tid >= off) ? s[tid - off] : 0;
        __syncthreads();
        s[tid] += t;
        __syncthreads();
    }
    if (tid < NBUCK) {
        int ex = s[tid] - v;     // exclusive
        bstart[tid] = ex;
        bcur[tid] = ex;
    }
    if (tid == 0) bstart[NBUCK] = N_EDGES;
}

// ---------------- A3: binned scatter of packed edges ----------------
// binned[pos] = (dst&127)<<17 | src   (src < 2^17)
__global__ void k_bin(const int* __restrict__ src, const int* __restrict__ dst,
                      int* __restrict__ bcur, unsigned int* __restrict__ binned) {
    __shared__ int ha[1024];
    __shared__ int hb[1024];
    __shared__ int gbase[NBUCK];
    __shared__ int lcur[NBUCK];
    int tid = threadIdx.x;
    int e0 = blockIdx.x * CHUNK;
    int e1 = e0 + CHUNK;
    if (e1 > N_EDGES) e1 = N_EDGES;
    for (int i = tid; i < 1024; i += 256) ha[i] = 0;
    __syncthreads();
    for (int e = e0 + tid; e < e1; e += 256)
        atomicAdd(&ha[dst[e] >> SHIFT], 1);
    __syncthreads();
    // inclusive scan over 1024 (ping-pong)
    int* a = ha;
    int* b = hb;
    for (int off = 1; off < 1024; off <<= 1) {
        for (int s = tid; s < 1024; s += 256)
            b[s] = a[s] + ((s >= off) ? a[s - off] : 0);
        __syncthreads();
        int* t = a; a = b; b = t;
    }
    for (int s = tid; s < NBUCK; s += 256) {
        int c = a[s] - ((s > 0) ? a[s - 1] : 0);
        lcur[s] = 0;
        gbase[s] = c ? atomicAdd(&bcur[s], c) : 0;
    }
    __syncthreads();
    for (int e = e0 + tid; e < e1; e += 256) {
        int d = dst[e];
        int bk = d >> SHIFT;
        int idx = atomicAdd(&lcur[bk], 1);
        binned[gbase[bk] + idx] =
            ((unsigned int)(d & (BWIDTH - 1)) << 17) | (unsigned int)src[e];
    }
}

// ---------------- B: per-bucket CSR (count, scan, rp/dinv, col scatter) ----------------
__global__ void k_csr(const unsigned int* __restrict__ binned, const int* __restrict__ bstart,
                      int* __restrict__ rp, float* __restrict__ dinv, int* __restrict__ col) {
    __shared__ int cnt[BWIDTH];
    __shared__ int s[BWIDTH];
    __shared__ int cur[BWIDTH];
    int tid = threadIdx.x;
    int b = blockIdx.x;
    int base = b << SHIFT;
    int e0 = bstart[b], e1 = bstart[b + 1];
    if (tid < BWIDTH) cnt[tid] = 0;
    __syncthreads();
    for (int e = e0 + tid; e < e1; e += 256)
        atomicAdd(&cnt[binned[e] >> 17], 1);
    __syncthreads();
    int v = 0;
    if (tid < BWIDTH) { v = cnt[tid]; s[tid] = v; }
    __syncthreads();
    for (int off = 1; off < BWIDTH; off <<= 1) {
        int t = 0;
        if (tid < BWIDTH && tid >= off) t = s[tid - off];
        __syncthreads();
        if (tid < BWIDTH) s[tid] += t;
        __syncthreads();
    }
    if (tid < BWIDTH) {
        int ex = s[tid] - v;     // exclusive
        cur[tid] = ex;
        int node = base + tid;
        if (node < N_NODES) {
            rp[node] = e0 + ex;
            dinv[node] = rsqrtf((float)(v + 1));
        }
    }
    if (b == 0 && tid == 0) rp[N_NODES] = N_EDGES;
    __syncthreads();
    for (int e = e0 + tid; e < e1; e += 256) {
        unsigned int w = binned[e];
        int ln = (int)(w >> 17);
        int p = atomicAdd(&cur[ln], 1);
        col[e0 + p] = (int)(w & 0x1FFFFu);
    }
}

// ---------------- h0s = dinv * (x @ W1), split-K x4 ----------------
// block = 256 = 4 waves; wave sp handles features [sp*128, sp*128+128) for 64 rows
#define XW_ROWS 64
__global__ void k_xw1(const float* __restrict__ x, const float* __restrict__ W,
                      const float* __restrict__ dinv, float* __restrict__ h0s) {
    __shared__ float red[4][XW_ROWS][HID + 1];   // +1 pad: kill 16-stride bank conflicts
    int lane = threadIdx.x & 63;
    int sp   = threadIdx.x >> 6;                 // wave-uniform split -> W via s_load
    int rowBase = blockIdx.x * XW_ROWS;
    int row = rowBase + lane;
    float acc[HID];
#pragma unroll
    for (int c = 0; c < HID; c++) acc[c] = 0.f;
    if (row < N_NODES) {
        const float4* x4 = (const float4*)(x + (size_t)row * F_IN + sp * (F_IN / 4));
        for (int k4 = 0; k4 < F_IN / 16; k4++) {   // 32 float4 loads
            float4 xv = x4[k4];
            int kb = sp * (F_IN / 4) + k4 * 4;
#pragma unroll
            for (int j = 0; j < 4; j++) {
                float xj = (j == 0) ? xv.x : (j == 1) ? xv.y : (j == 2) ? xv.z : xv.w;
#pragma unroll
                for (int c = 0; c < HID; c++)
                    acc[c] += xj * W[(kb + j) * HID + c];
            }
        }
    }
#pragma unroll
    for (int c = 0; c < HID; c++) red[sp][lane][c] = acc[c];
    __syncthreads();
#pragma unroll
    for (int p = 0; p < 4; p++) {
        int f = threadIdx.x + p * 256;   // 0..1023
        int r = f >> 4, c = f & 15;
        int node = rowBase + r;
        if (node < N_NODES) {
            float v = red[0][r][c] + red[1][r][c] + red[2][r][c] + red[3][r][c];
            h0s[(size_t)node * HID + c] = dinv[node] * v;
        }
    }
}

// ---------------- aggregate 1: h1 = relu(dv*(h0s[n] + sum h0s[col]) + b1) ----------------
__global__ void k_agg1(const float* __restrict__ h0s, const int* __restrict__ rp,
                       const int* __restrict__ col, const float* __restrict__ dinv,
                       const float* __restrict__ b1, float* __restrict__ h1) {
    int t = blockIdx.x * blockDim.x + threadIdx.x;
    int node = t >> 4;
    int c = t & 15;
    if (node >= N_NODES) return;
    float acc = h0s[(size_t)node * HID + c];   // self loop (pre-scaled)
    int e0 = rp[node], e1 = rp[node + 1];
    int e = e0;
    for (; e + 1 < e1; e += 2) {
        int s0 = col[e], s1 = col[e + 1];
        float v0 = h0s[(size_t)s0 * HID + c];
        float v1 = h0s[(size_t)s1 * HID + c];
        acc += v0;
        acc += v1;
    }
    if (e < e1) acc += h0s[(size_t)col[e] * HID + c];
    float o = dinv[node] * acc + b1[c];
    h1[(size_t)node * HID + c] = fmaxf(o, 0.f);
}

// ---------------- 10 fused hops + zs = dinv * (h @ W2) ----------------
__global__ void k_hops(const float* __restrict__ h1, const float* __restrict__ Wl,
                       const float* __restrict__ bl, const float* __restrict__ W2,
                       const float* __restrict__ dinv, float* __restrict__ zs) {
    int node = blockIdx.x * blockDim.x + threadIdx.x;
    if (node >= N_NODES) return;
    float h[HID];
    const float4* h4 = (const float4*)(h1 + (size_t)node * HID);
#pragma unroll
    for (int q = 0; q < HID / 4; q++) {
        float4 v = h4[q];
        h[q * 4 + 0] = v.x; h[q * 4 + 1] = v.y;
        h[q * 4 + 2] = v.z; h[q * 4 + 3] = v.w;
    }
    for (int it = 0; it < K_HOPS; it++) {
        float tm[HID];
#pragma unroll
        for (int c = 0; c < HID; c++) tm[c] = bl[c];
#pragma unroll
        for (int k = 0; k < HID; k++) {
            float hk = h[k];
#pragma unroll
            for (int c = 0; c < HID; c++) tm[c] += hk * Wl[k * HID + c];
        }
#pragma unroll
        for (int c = 0; c < HID; c++)
            h[c] = ALPHA * fmaxf(tm[c], 0.f) + (1.f - ALPHA) * h[c];
    }
    float dv = dinv[node];
    float zz[8];
#pragma unroll
    for (int c = 0; c < 8; c++) zz[c] = 0.f;
#pragma unroll
    for (int k = 0; k < HID; k++) {
        float hk = h[k];
#pragma unroll
        for (int c = 0; c < NCLS; c++) zz[c] += hk * W2[k * NCLS + c];
    }
    float4* z4 = (float4*)(zs + (size_t)node * 8);
    float4 v0, v1;
    v0.x = dv * zz[0]; v0.y = dv * zz[1]; v0.z = dv * zz[2]; v0.w = dv * zz[3];
    v1.x = dv * zz[4]; v1.y = dv * zz[5]; v1.z = dv * zz[6]; v1.w = 0.f;
    z4[0] = v0; z4[1] = v1;
}

// ---------------- aggregate 2 + bias + log_softmax ----------------
__global__ void k_agg2(const float* __restrict__ zs, const int* __restrict__ rp,
                       const int* __restrict__ col, const float* __restrict__ dinv,
                       const float* __restrict__ b2, float* __restrict__ out) {
    int t = blockIdx.x * blockDim.x + threadIdx.x;
    int node = t >> 3;
    int c = t & 7;
    if (node >= N_NODES) return;
    float acc = zs[(size_t)node * 8 + c];      // self loop (pre-scaled; pad lane reads 0)
    int e0 = rp[node], e1 = rp[node + 1];
    int e = e0;
    for (; e + 1 < e1; e += 2) {
        int s0 = col[e], s1 = col[e + 1];
        float v0 = zs[(size_t)s0 * 8 + c];
        float v1 = zs[(size_t)s1 * 8 + c];
        acc += v0;
        acc += v1;
    }
    if (e < e1) acc += zs[(size_t)col[e] * 8 + c];
    float o = dinv[node] * acc + ((c < NCLS) ? b2[c] : 0.f);
    float val = (c < NCLS) ? o : -INFINITY;
    float m = val;
    m = fmaxf(m, __shfl_xor(m, 1));
    m = fmaxf(m, __shfl_xor(m, 2));
    m = fmaxf(m, __shfl_xor(m, 4));
    float ex = (c < NCLS) ? expf(o - m) : 0.f;
    float ss = ex;
    ss += __shfl_xor(ss, 1);
    ss += __shfl_xor(ss, 2);
    ss += __shfl_xor(ss, 4);
    if (c < NCLS) out[(size_t)node * NCLS + c] = o - m - logf(ss);
}

extern "C" void kernel_launch(void* const* d_in, const int* in_sizes, int n_in,
                              void* d_out, int out_size, void* d_ws, size_t ws_size,
                              hipStream_t stream) {
    const float* x  = (const float*)d_in[0];
    const int*   ei = (const int*)d_in[1];
    const float* W1 = (const float*)d_in[2];
    const float* b1 = (const float*)d_in[3];
    const float* Wl = (const float*)d_in[4];
    const float* bl = (const float*)d_in[5];
    const float* W2 = (const float*)d_in[6];
    const float* b2 = (const float*)d_in[7];
    float* out = (float*)d_out;

    int*   wsI = (int*)d_ws;
    float* wsF = (float*)d_ws;
    int*          bcnt   = wsI + OFF_BCNT;
    int*          bstart = wsI + OFF_BSTART;
    int*          bcur   = wsI + OFF_BCUR;
    int*          rp     = wsI + OFF_RP;
    float*        dinv   = wsF + OFF_DINV;
    int*          col    = wsI + OFF_COL;
    unsigned int* binned = (unsigned int*)(wsI + OFF_BINNED);
    float*        h0s    = wsF + OFF_H0;   // aliases binned (binned dead after k_csr)
    float*        h1     = wsF + OFF_H1;
    float*        zs     = wsF + OFF_Z;

    const int* src = ei;
    const int* dst = ei + N_EDGES;

    hipMemsetAsync(bcnt, 0, NBUCK * sizeof(int), stream);

    k_bhist<<<1024, 256, 0, stream>>>(dst, bcnt);
    k_bscan<<<1, 1024, 0, stream>>>(bcnt, bstart, bcur);
    k_bin<<<A3_BLOCKS, 256, 0, stream>>>(src, dst, bcur, binned);
    k_csr<<<NBUCK, 256, 0, stream>>>(binned, bstart, rp, dinv, col);
    k_xw1<<<(N_NODES + XW_ROWS - 1) / XW_ROWS, 256, 0, stream>>>(x, W1, dinv, h0s);
    k_agg1<<<(N_NODES * 16 + 255) / 256, 256, 0, stream>>>(h0s, rp, col, dinv, b1, h1);
    k_hops<<<(N_NODES + 255) / 256, 256, 0, stream>>>(h1, Wl, bl, W2, dinv, zs);
    k_agg2<<<(N_NODES * 8 + 255) / 256, 256, 0, stream>>>(zs, rp, col, dinv, b2, out);
}

// Round 4
// 609.734 us; speedup vs baseline: 1.4733x; 1.0556x over previous
//
#include <hip/hip_runtime.h>
#include <math.h>

#define N_NODES 100000
#define N_EDGES 3200000
#define F_IN    512
#define HID     16
#define NCLS    7
#define ALPHA   0.1f
#define K_HOPS  10

// bucketing: 128 nodes per bucket
#define SHIFT   7
#define BWIDTH  128
#define NBUCK   ((N_NODES + BWIDTH - 1) / BWIDTH)   // 782
#define CHUNK   8192
#define A3_BLOCKS ((N_EDGES + CHUNK - 1) / CHUNK)   // 391

// ---- workspace layout (4-byte element offsets) ----
#define OFF_BCNT    0u         // int[782]
#define OFF_BSTART  1024u      // int[783]
#define OFF_BCUR    2048u      // int[782]
#define OFF_RP      3072u      // int[100001]
#define OFF_DINV    103424u    // float[100000]
#define OFF_COL     203776u    // int[3200000]
#define OFF_BINNED  3403776u   // uint[3200000]  (aliased with h0s below)
#define OFF_H0      3403776u   // float[100000*16]   -- written AFTER k_csr reads binned
#define OFF_H1      5003776u   // float[100000*16]
#define OFF_Z       6603776u   // float[100000*8]
// total = 7403776 elems = 29.6 MB

// ---------------- A1: global bucket histogram ----------------
__global__ void k_bhist(const int* __restrict__ dst, int* __restrict__ bcnt) {
    __shared__ int h[NBUCK];
    int tid = threadIdx.x;
    for (int i = tid; i < NBUCK; i += 256) h[i] = 0;
    __syncthreads();
    for (int e = blockIdx.x * 256 + tid; e < N_EDGES; e += gridDim.x * 256)
        atomicAdd(&h[dst[e] >> SHIFT], 1);
    __syncthreads();
    for (int i = tid; i < NBUCK; i += 256) {
        int v = h[i];
        if (v) atomicAdd(&bcnt[i], v);
    }
}

// ---------------- A2: scan bucket counts ----------------
__global__ void k_bscan(const int* __restrict__ bcnt, int* __restrict__ bstart,
                        int* __restrict__ bcur) {
    __shared__ int s[1024];
    int tid = threadIdx.x;
    int v = (tid < NBUCK) ? bcnt[tid] : 0;
    s[tid] = v;
    __syncthreads();
    for (int off = 1; off < 1024; off <<= 1) {
        int t = (tid >= off) ? s[tid - off] : 0;
        __syncthreads();
        s[tid] += t;
        __syncthreads();
    }
    if (tid < NBUCK) {
        int ex = s[tid] - v;     // exclusive
        bstart[tid] = ex;
        bcur[tid] = ex;
    }
    if (tid == 0) bstart[NBUCK] = N_EDGES;
}

// ---------------- A3: binned scatter of packed edges ----------------
// binned[pos] = (dst&127)<<17 | src   (src < 2^17)
__global__ void k_bin(const int* __restrict__ src, const int* __restrict__ dst,
                      int* __restrict__ bcur, unsigned int* __restrict__ binned) {
    __shared__ int ha[1024];
    __shared__ int hb[1024];
    __shared__ int gbase[NBUCK];
    __shared__ int lcur[NBUCK];
    int tid = threadIdx.x;
    int e0 = blockIdx.x * CHUNK;
    int e1 = e0 + CHUNK;
    if (e1 > N_EDGES) e1 = N_EDGES;
    for (int i = tid; i < 1024; i += 256) ha[i] = 0;
    __syncthreads();
    for (int e = e0 + tid; e < e1; e += 256)
        atomicAdd(&ha[dst[e] >> SHIFT], 1);
    __syncthreads();
    int* a = ha;
    int* b = hb;
    for (int off = 1; off < 1024; off <<= 1) {
        for (int s = tid; s < 1024; s += 256)
            b[s] = a[s] + ((s >= off) ? a[s - off] : 0);
        __syncthreads();
        int* t = a; a = b; b = t;
    }
    for (int s = tid; s < NBUCK; s += 256) {
        int c = a[s] - ((s > 0) ? a[s - 1] : 0);
        lcur[s] = 0;
        gbase[s] = c ? atomicAdd(&bcur[s], c) : 0;
    }
    __syncthreads();
    for (int e = e0 + tid; e < e1; e += 256) {
        int d = dst[e];
        int bk = d >> SHIFT;
        int idx = atomicAdd(&lcur[bk], 1);
        binned[gbase[bk] + idx] =
            ((unsigned int)(d & (BWIDTH - 1)) << 17) | (unsigned int)src[e];
    }
}

// ---------------- B: per-bucket CSR ----------------
__global__ void k_csr(const unsigned int* __restrict__ binned, const int* __restrict__ bstart,
                      int* __restrict__ rp, float* __restrict__ dinv, int* __restrict__ col) {
    __shared__ int cnt[BWIDTH];
    __shared__ int s[BWIDTH];
    __shared__ int cur[BWIDTH];
    int tid = threadIdx.x;
    int b = blockIdx.x;
    int base = b << SHIFT;
    int e0 = bstart[b], e1 = bstart[b + 1];
    if (tid < BWIDTH) cnt[tid] = 0;
    __syncthreads();
    for (int e = e0 + tid; e < e1; e += 256)
        atomicAdd(&cnt[binned[e] >> 17], 1);
    __syncthreads();
    int v = 0;
    if (tid < BWIDTH) { v = cnt[tid]; s[tid] = v; }
    __syncthreads();
    for (int off = 1; off < BWIDTH; off <<= 1) {
        int t = 0;
        if (tid < BWIDTH && tid >= off) t = s[tid - off];
        __syncthreads();
        if (tid < BWIDTH) s[tid] += t;
        __syncthreads();
    }
    if (tid < BWIDTH) {
        int ex = s[tid] - v;
        cur[tid] = ex;
        int node = base + tid;
        if (node < N_NODES) {
            rp[node] = e0 + ex;
            dinv[node] = rsqrtf((float)(v + 1));
        }
    }
    if (b == 0 && tid == 0) rp[N_NODES] = N_EDGES;
    __syncthreads();
    for (int e = e0 + tid; e < e1; e += 256) {
        unsigned int w = binned[e];
        int ln = (int)(w >> 17);
        int p = atomicAdd(&cur[ln], 1);
        col[e0 + p] = (int)(w & 0x1FFFFu);
    }
}

// ---------------- h0s = dinv * (x @ W1): coalesced LDS-tiled GEMM ----------------
// block = 256 thr, 64 rows; K-tile = 32; xT[k][r] in LDS, row-stride 65 (<=2-way conflicts)
// staging: 8 consecutive lanes read 128B contiguous (full lines); compute: lanes span r.
#define XW_ROWS 64
#define XW_KT   32
#define XW_S    65
#define XW_NT   (F_IN / XW_KT)   // 16 tiles
__global__ void k_xw1(const float* __restrict__ x, const float* __restrict__ W,
                      const float* __restrict__ dinv, float* __restrict__ h0s) {
    __shared__ float xT[2][XW_KT * XW_S];    // 2 x 8320 B
    int tid = threadIdx.x;
    int rowBase = blockIdx.x * XW_ROWS;

    // staging mapping: float4 f0 = tid (rf0 = tid>>3, kq = tid&7), f1 = tid+256 (rf1 = rf0+32)
    int rf0 = tid >> 3, kq = tid & 7;
    int rf1 = rf0 + 32;
    bool v0 = (rowBase + rf0) < N_NODES;
    bool v1 = (rowBase + rf1) < N_NODES;
    const float* xrow0 = x + (size_t)(rowBase + rf0) * F_IN;
    const float* xrow1 = x + (size_t)(rowBase + rf1) * F_IN;

    // compute mapping: wave cg (c-group of 4), lane r = row in tile
    int r  = tid & 63;
    int cg = __builtin_amdgcn_readfirstlane(tid >> 6);   // force wave-uniform -> s_load W
    const float4* W4 = (const float4*)W;                 // W4[k*4 + cg] = W[k][cg*4..+3]

    float4 zero4 = make_float4(0.f, 0.f, 0.f, 0.f);
    float4 acc = zero4;
    float4 ld0 = v0 ? ((const float4*)xrow0)[kq] : zero4;
    float4 ld1 = v1 ? ((const float4*)xrow1)[kq] : zero4;

    for (int kt = 0; kt < XW_NT; kt++) {
        int buf = kt & 1;
        float* xb = xT[buf];
        int kb = kq * 4;
        // transpose-store staged regs (stride XW_S: <=2-way bank aliasing = free)
        xb[(kb + 0) * XW_S + rf0] = ld0.x;
        xb[(kb + 1) * XW_S + rf0] = ld0.y;
        xb[(kb + 2) * XW_S + rf0] = ld0.z;
        xb[(kb + 3) * XW_S + rf0] = ld0.w;
        xb[(kb + 0) * XW_S + rf1] = ld1.x;
        xb[(kb + 1) * XW_S + rf1] = ld1.y;
        xb[(kb + 2) * XW_S + rf1] = ld1.z;
        xb[(kb + 3) * XW_S + rf1] = ld1.w;
        // prefetch next tile (overlaps this tile's compute; waited at next store)
        if (kt + 1 < XW_NT) {
            const float4* p0 = (const float4*)(xrow0 + (kt + 1) * XW_KT);
            const float4* p1 = (const float4*)(xrow1 + (kt + 1) * XW_KT);
            ld0 = v0 ? p0[kq] : zero4;
            ld1 = v1 ? p1[kq] : zero4;
        }
        __syncthreads();   // single barrier per tile (double buffer makes it safe)
        const float* xr = &xb[r];
#pragma unroll
        for (int k = 0; k < XW_KT; k++) {
            float xv = xr[k * XW_S];
            float4 w4 = W4[(kt * XW_KT + k) * 4 + cg];
            acc.x += xv * w4.x;
            acc.y += xv * w4.y;
            acc.z += xv * w4.z;
            acc.w += xv * w4.w;
        }
    }
    int node = rowBase + r;
    if (node < N_NODES) {
        float dv = dinv[node];
        float4 o;
        o.x = dv * acc.x; o.y = dv * acc.y; o.z = dv * acc.z; o.w = dv * acc.w;
        ((float4*)h0s)[(size_t)node * 4 + cg] = o;
    }
}

// ---------------- aggregate 1: one wave per node ----------------
// lane = c + 16*eo; 4 edges in flight; butterfly-reduce over eo.
__global__ void k_agg1(const float* __restrict__ h0s, const int* __restrict__ rp,
                       const int* __restrict__ col, const float* __restrict__ dinv,
                       const float* __restrict__ b1, float* __restrict__ h1) {
    int node = (blockIdx.x * blockDim.x + threadIdx.x) >> 6;
    if (node >= N_NODES) return;
    int lane = threadIdx.x & 63;
    int c = lane & 15, eo = lane >> 4;
    int e0 = rp[node], e1 = rp[node + 1];
    float acc = 0.f;
    for (int e = e0 + eo; e < e1; e += 4)
        acc += h0s[(size_t)col[e] * HID + c];
    acc += __shfl_xor(acc, 16);
    acc += __shfl_xor(acc, 32);
    float o = dinv[node] * (acc + h0s[(size_t)node * HID + c]) + b1[c];
    if (eo == 0) h1[(size_t)node * HID + c] = fmaxf(o, 0.f);
}

// ---------------- 10 fused hops + zs = dinv * (h @ W2) ----------------
__global__ void k_hops(const float* __restrict__ h1, const float* __restrict__ Wl,
                       const float* __restrict__ bl, const float* __restrict__ W2,
                       const float* __restrict__ dinv, float* __restrict__ zs) {
    int node = blockIdx.x * blockDim.x + threadIdx.x;
    if (node >= N_NODES) return;
    float h[HID];
    const float4* h4 = (const float4*)(h1 + (size_t)node * HID);
#pragma unroll
    for (int q = 0; q < HID / 4; q++) {
        float4 v = h4[q];
        h[q * 4 + 0] = v.x; h[q * 4 + 1] = v.y;
        h[q * 4 + 2] = v.z; h[q * 4 + 3] = v.w;
    }
    for (int it = 0; it < K_HOPS; it++) {
        float tm[HID];
#pragma unroll
        for (int c = 0; c < HID; c++) tm[c] = bl[c];
#pragma unroll
        for (int k = 0; k < HID; k++) {
            float hk = h[k];
#pragma unroll
            for (int c = 0; c < HID; c++) tm[c] += hk * Wl[k * HID + c];
        }
#pragma unroll
        for (int c = 0; c < HID; c++)
            h[c] = ALPHA * fmaxf(tm[c], 0.f) + (1.f - ALPHA) * h[c];
    }
    float dv = dinv[node];
    float zz[8];
#pragma unroll
    for (int c = 0; c < 8; c++) zz[c] = 0.f;
#pragma unroll
    for (int k = 0; k < HID; k++) {
        float hk = h[k];
#pragma unroll
        for (int c = 0; c < NCLS; c++) zz[c] += hk * W2[k * NCLS + c];
    }
    float4* z4 = (float4*)(zs + (size_t)node * 8);
    float4 v0, v1;
    v0.x = dv * zz[0]; v0.y = dv * zz[1]; v0.z = dv * zz[2]; v0.w = dv * zz[3];
    v1.x = dv * zz[4]; v1.y = dv * zz[5]; v1.z = dv * zz[6]; v1.w = 0.f;
    z4[0] = v0; z4[1] = v1;
}

// ---------------- aggregate 2 + log_softmax: one wave per node ----------------
// lane = c + 8*eo; 8 edges in flight; butterfly over eo then softmax over c.
__global__ void k_agg2(const float* __restrict__ zs, const int* __restrict__ rp,
                       const int* __restrict__ col, const float* __restrict__ dinv,
                       const float* __restrict__ b2, float* __restrict__ out) {
    int node = (blockIdx.x * blockDim.x + threadIdx.x) >> 6;
    if (node >= N_NODES) return;
    int lane = threadIdx.x & 63;
    int c = lane & 7, eo = lane >> 3;
    int e0 = rp[node], e1 = rp[node + 1];
    float acc = 0.f;
    for (int e = e0 + eo; e < e1; e += 8)
        acc += zs[(size_t)col[e] * 8 + c];
    acc += __shfl_xor(acc, 8);
    acc += __shfl_xor(acc, 16);
    acc += __shfl_xor(acc, 32);
    float o = dinv[node] * (acc + zs[(size_t)node * 8 + c]) + ((c < NCLS) ? b2[c] : 0.f);
    float val = (c < NCLS) ? o : -INFINITY;
    float m = val;
    m = fmaxf(m, __shfl_xor(m, 1));
    m = fmaxf(m, __shfl_xor(m, 2));
    m = fmaxf(m, __shfl_xor(m, 4));
    float ex = (c < NCLS) ? expf(o - m) : 0.f;
    float ss = ex;
    ss += __shfl_xor(ss, 1);
    ss += __shfl_xor(ss, 2);
    ss += __shfl_xor(ss, 4);
    if (eo == 0 && c < NCLS) out[(size_t)node * NCLS + c] = o - m - logf(ss);
}

extern "C" void kernel_launch(void* const* d_in, const int* in_sizes, int n_in,
                              void* d_out, int out_size, void* d_ws, size_t ws_size,
                              hipStream_t stream) {
    const float* x  = (const float*)d_in[0];
    const int*   ei = (const int*)d_in[1];
    const float* W1 = (const float*)d_in[2];
    const float* b1 = (const float*)d_in[3];
    const float* Wl = (const float*)d_in[4];
    const float* bl = (const float*)d_in[5];
    const float* W2 = (const float*)d_in[6];
    const float* b2 = (const float*)d_in[7];
    float* out = (float*)d_out;

    int*   wsI = (int*)d_ws;
    float* wsF = (float*)d_ws;
    int*          bcnt   = wsI + OFF_BCNT;
    int*          bstart = wsI + OFF_BSTART;
    int*          bcur   = wsI + OFF_BCUR;
    int*          rp     = wsI + OFF_RP;
    float*        dinv   = wsF + OFF_DINV;
    int*          col    = wsI + OFF_COL;
    unsigned int* binned = (unsigned int*)(wsI + OFF_BINNED);
    float*        h0s    = wsF + OFF_H0;   // aliases binned (binned dead after k_csr)
    float*        h1     = wsF + OFF_H1;
    float*        zs     = wsF + OFF_Z;

    const int* src = ei;
    const int* dst = ei + N_EDGES;

    hipMemsetAsync(bcnt, 0, NBUCK * sizeof(int), stream);

    k_bhist<<<1024, 256, 0, stream>>>(dst, bcnt);
    k_bscan<<<1, 1024, 0, stream>>>(bcnt, bstart, bcur);
    k_bin<<<A3_BLOCKS, 256, 0, stream>>>(src, dst, bcur, binned);
    k_csr<<<NBUCK, 256, 0, stream>>>(binned, bstart, rp, dinv, col);
    k_xw1<<<(N_NODES + XW_ROWS - 1) / XW_ROWS, 256, 0, stream>>>(x, W1, dinv, h0s);
    k_agg1<<<(N_NODES * 64 + 255) / 256, 256, 0, stream>>>(h0s, rp, col, dinv, b1, h1);
    k_hops<<<(N_NODES + 255) / 256, 256, 0, stream>>>(h1, Wl, bl, W2, dinv, zs);
    k_agg2<<<(N_NODES * 64 + 255) / 256, 256, 0, stream>>>(zs, rp, col, dinv, b2, out);
}